// Round 1
// baseline (1196.882 us; speedup 1.0000x reference)
//
#include <hip/hip_runtime.h>

#define B_   4
#define CIN  32
#define COUT 64
#define T_   8
#define D_   32
#define H_   64
#define W_   64

#define TD 2
#define TH 8
#define TW 16

// Keff layout: [b][og][c][oi][r]  (og=o>>4, oi=o&15, r = i*9+j*3+k)
__global__ void keff_kernel(const float* __restrict__ stencils,
                            const float* __restrict__ weight,
                            float* __restrict__ keff) {
    int i = blockIdx.x * blockDim.x + threadIdx.x;
    const int N = B_ * COUT * CIN * 27;
    if (i >= N) return;
    int r  = i % 27;
    int oi = (i / 27) % 16;
    int c  = (i / (27 * 16)) % CIN;
    int og = (i / (27 * 16 * CIN)) % 4;
    int b  = i / (27 * 16 * CIN * 4);
    int o  = og * 16 + oi;
    float acc = 0.f;
    #pragma unroll
    for (int t = 0; t < T_; ++t)
        acc += weight[(o * CIN + c) * T_ + t] * stencils[(b * T_ + t) * 27 + r];
    keff[i] = acc;
}

__global__ __launch_bounds__(256) void conv_kernel(
    const float* __restrict__ x, const float* __restrict__ keff,
    const float* __restrict__ bias, float* __restrict__ out) {
    __shared__ float tile[4 * 10 * 18];   // (TD+2) x (TH+2) x (TW+2)

    int bx = blockIdx.x;       // spatial tile id
    int og = blockIdx.y;       // cout group (16 couts)
    int b  = blockIdx.z;
    int wt = bx & 3, ht = (bx >> 2) & 7, dt = bx >> 5;
    int w0 = wt * TW, h0 = ht * TH, d0 = dt * TD;
    int tid = threadIdx.x;
    int dx = tid & 15, dy = (tid >> 4) & 7, dz = tid >> 7;

    float acc[16];
    #pragma unroll
    for (int oi = 0; oi < 16; ++oi) acc[oi] = 0.f;

    for (int c = 0; c < CIN; ++c) {
        __syncthreads();
        const float* xb = x + (size_t)(b * CIN + c) * (D_ * H_ * W_);
        for (int idx = tid; idx < 720; idx += 256) {
            int xx = idx % 18;
            int yy = (idx / 18) % 10;
            int zz = idx / 180;
            int gw = w0 - 1 + xx, gh = h0 - 1 + yy, gd = d0 - 1 + zz;
            float v = 0.f;
            if ((unsigned)gw < W_ && (unsigned)gh < H_ && (unsigned)gd < D_)
                v = xb[(gd * H_ + gh) * W_ + gw];
            tile[idx] = v;
        }
        __syncthreads();
        // wave-uniform base -> compiler emits scalar loads for keff
        const float* kb = keff + ((b * 4 + og) * CIN + c) * 432;
        #pragma unroll
        for (int r = 0; r < 27; ++r) {
            int i = r / 9, j = (r / 3) % 3, k = r % 3;
            float xv = tile[(dz + i) * 180 + (dy + j) * 18 + (dx + k)];
            #pragma unroll
            for (int oi = 0; oi < 16; ++oi)
                acc[oi] += xv * kb[oi * 27 + r];
        }
    }

    int o0 = og * 16;
    int d = d0 + dz, h = h0 + dy, w = w0 + dx;
    size_t base = (((size_t)(b * COUT + o0) * D_ + d) * H_ + h) * W_ + w;
    #pragma unroll
    for (int oi = 0; oi < 16; ++oi)
        out[base + (size_t)oi * (D_ * H_ * W_)] = acc[oi] + bias[o0 + oi];
}

extern "C" void kernel_launch(void* const* d_in, const int* in_sizes, int n_in,
                              void* d_out, int out_size, void* d_ws, size_t ws_size,
                              hipStream_t stream) {
    const float* x        = (const float*)d_in[0];
    const float* stencils = (const float*)d_in[1];
    const float* weight   = (const float*)d_in[2];
    const float* bias     = (const float*)d_in[3];
    float* out  = (float*)d_out;
    float* keff = (float*)d_ws;   // 221184 floats = 864 KB

    const int NK = B_ * COUT * CIN * 27;
    keff_kernel<<<(NK + 255) / 256, 256, 0, stream>>>(stencils, weight, keff);

    dim3 grid(512, 4, 4);   // (spatial tiles, cout groups, batch)
    conv_kernel<<<grid, 256, 0, stream>>>(x, keff, bias, out);
}

// Round 2
// 257.907 us; speedup vs baseline: 4.6407x; 4.6407x over previous
//
#include <hip/hip_runtime.h>

typedef short bf16x8 __attribute__((ext_vector_type(8)));
typedef float f32x16 __attribute__((ext_vector_type(16)));

typedef const __attribute__((address_space(1))) unsigned int GUint;
typedef __attribute__((address_space(3))) unsigned int LUint;

#define XT_BYTES 37914624ull   // 4b * 34zp * 66yp * 66xp * 64B

__device__ __forceinline__ unsigned short f2bf(float f) {
    unsigned u = __float_as_uint(f);
    return (unsigned short)((u + 0x7FFFu + ((u >> 16) & 1u)) >> 16);
}

// ---- pass 1: pad+transpose x (B,Cin,D,H,W) fp32 -> xt[b][zp][yp][xp][c] bf16,
// 16B chunks (8ch) swizzled: chunk q of point xp stored at slot q ^ ((xp>>1)&3).
__global__ __launch_bounds__(256) void prep_x(const float* __restrict__ x,
                                              uint4* __restrict__ xt) {
    int yp = blockIdx.x;    // 0..65
    int zp = blockIdx.y;    // 0..33
    int b  = blockIdx.z;    // 0..3
    int t  = threadIdx.x;
    size_t rowbase = ((((size_t)b * 34 + zp) * 66 + yp) * 66) * 4;  // uint4 units
    bool in_zy = (zp >= 1 && zp <= 32 && yp >= 1 && yp <= 64);
    for (int idx = t; idx < 264; idx += 256) {
        int q, xp;
        if (idx < 256) { q = idx >> 6; xp = idx & 63; }
        else { int k = idx - 256; q = k >> 1; xp = 64 + (k & 1); }
        uint4 v = make_uint4(0u, 0u, 0u, 0u);
        if (in_zy && xp >= 1 && xp <= 64) {
            int d = zp - 1, h = yp - 1, w = xp - 1;
            const float* xb = x + ((((size_t)b * 32 + q * 8) * 32 + d) * 64 + h) * 64 + w;
            unsigned short us[8];
            #pragma unroll
            for (int j = 0; j < 8; ++j)
                us[j] = f2bf(xb[(size_t)j * 131072]);
            v.x = us[0] | ((unsigned)us[1] << 16);
            v.y = us[2] | ((unsigned)us[3] << 16);
            v.z = us[4] | ((unsigned)us[5] << 16);
            v.w = us[6] | ((unsigned)us[7] << 16);
        }
        int pos = q ^ ((xp >> 1) & 3);
        xt[rowbase + (size_t)xp * 4 + pos] = v;
    }
}

// ---- pass 2: keff[b][r][o][c] bf16 = sum_t weight[o][c][t]*stencils[b][t][r],
// chunk q of cout o stored at slot q ^ ((o>>1)&3).
__global__ __launch_bounds__(256) void prep_keff(const float* __restrict__ stencils,
                                                 const float* __restrict__ weight,
                                                 uint4* __restrict__ keffg) {
    int i = blockIdx.x * 256 + threadIdx.x;   // chunk id = ((b*27+r)*64+o)*4+q
    if (i >= 4 * 27 * 64 * 4) return;
    int q = i & 3;
    int o = (i >> 2) & 63;
    int br = i >> 8;
    int r = br % 27, b = br / 27;
    float st[8];
    #pragma unroll
    for (int t = 0; t < 8; ++t) st[t] = stencils[((size_t)b * 8 + t) * 27 + r];
    unsigned short us[8];
    #pragma unroll
    for (int j = 0; j < 8; ++j) {
        const float* wp = weight + ((size_t)o * 32 + q * 8 + j) * 8;
        float acc = 0.f;
        #pragma unroll
        for (int t = 0; t < 8; ++t) acc += wp[t] * st[t];
        us[j] = f2bf(acc);
    }
    uint4 v;
    v.x = us[0] | ((unsigned)us[1] << 16);
    v.y = us[2] | ((unsigned)us[3] << 16);
    v.z = us[4] | ((unsigned)us[5] << 16);
    v.w = us[6] | ((unsigned)us[7] << 16);
    int pos = q ^ ((o >> 1) & 3);
    keffg[(((size_t)br * 64 + o) << 2) + pos] = v;
}

// ---- pass 3: MFMA conv. Block = 64 couts x (2d x 4h x 32w) positions.
// LDS: x tile 4z*6y*34x*64B = 52224B, keff dbuf 2*4096B. Total 60416B -> 2 blk/CU.
#define KBUF 52224

__global__ __launch_bounds__(256, 2) void conv_mfma(
    const uint4* __restrict__ xt, const uint4* __restrict__ keffg,
    const float* __restrict__ bias, float* __restrict__ out) {
    __shared__ __align__(1024) char smem[60416];

    int n = blockIdx.x;
    int xcd = n & 7, local = n >> 3;
    int dt = local & 15;
    int cmb = (local >> 4) | (xcd << 4);
    int ht = cmb & 15, wt = (cmb >> 4) & 1, b = cmb >> 5;

    int tid = threadIdx.x;
    int lane = tid & 63, wid = tid >> 6;
    int nlo = lane & 31, kh = lane >> 5;

    const char* xtc = (const char*)xt;
    const char* kfc = (const char*)keffg;

    // prologue: stage x tile (rows: z 0..3, yy 0..5; 136 chunks/row)
    for (int row = wid; row < 24; row += 4) {
        int z = row / 6, yy = row - z * 6;
        size_t gbase = ((((size_t)b * 34 + dt * 2 + z) * 66 + ht * 4 + yy) * 66 + wt * 32) * 64;
        int ldsbase = row * 2176;
        #pragma unroll
        for (int cb = 0; cb < 136; cb += 64) {
            int rem = 136 - cb;
            if (lane < rem) {
                __builtin_amdgcn_global_load_lds(
                    (GUint*)(xtc + gbase + (size_t)(cb + lane) * 16),
                    (LUint*)(smem + ldsbase + cb * 16), 16, 0, 0);
            }
        }
    }
    // stage keff[r=0] into buf0 (each wave: 64 chunks)
    __builtin_amdgcn_global_load_lds(
        (GUint*)(kfc + (size_t)(b * 27) * 4096 + (size_t)(wid * 64 + lane) * 16),
        (LUint*)(smem + KBUF + wid * 1024), 16, 0, 0);
    __syncthreads();

    // per-wave tile: 2 M-tiles (o 0-31,32-63) x 2 N-tiles (rows ys, ys+1)
    int z = wid >> 1;
    int ys = (wid & 1) << 1;

    int Badr[2][3];
    #pragma unroll
    for (int s = 0; s < 2; ++s)
        #pragma unroll
        for (int k3 = 0; k3 < 3; ++k3) {
            int xl = nlo + k3;
            int pos = (s * 2 + kh) ^ ((xl >> 1) & 3);
            Badr[s][k3] = (z * 6 + ys) * 2176 + xl * 64 + (pos << 4);
        }
    int Aadr[2];
    #pragma unroll
    for (int s = 0; s < 2; ++s)
        Aadr[s] = nlo * 64 + (((s * 2 + kh) ^ ((nlo >> 1) & 3)) << 4);

    f32x16 acc[2][2];
    #pragma unroll
    for (int mt = 0; mt < 2; ++mt)
        #pragma unroll
        for (int nt = 0; nt < 2; ++nt)
            #pragma unroll
            for (int e = 0; e < 16; ++e) acc[mt][nt][e] = 0.f;

    #pragma unroll
    for (int r = 0; r < 27; ++r) {
        int i3 = r / 9, j3 = (r / 3) % 3, k3 = r % 3;
        if (r < 26) {   // prefetch keff[r+1] into other buffer
            __builtin_amdgcn_global_load_lds(
                (GUint*)(kfc + (size_t)(b * 27 + r + 1) * 4096 + (size_t)(wid * 64 + lane) * 16),
                (LUint*)(smem + KBUF + (((r + 1) & 1) << 12) + wid * 1024), 16, 0, 0);
        }
        int kbase = KBUF + ((r & 1) << 12);
        #pragma unroll
        for (int s = 0; s < 2; ++s) {
            bf16x8 a0 = *(const bf16x8*)(smem + kbase + Aadr[s]);
            bf16x8 a1 = *(const bf16x8*)(smem + kbase + 2048 + Aadr[s]);
            #pragma unroll
            for (int nt = 0; nt < 2; ++nt) {
                bf16x8 bb = *(const bf16x8*)(smem + (i3 * 6 + j3 + nt) * 2176 + Badr[s][k3]);
                acc[0][nt] = __builtin_amdgcn_mfma_f32_32x32x16_bf16(a0, bb, acc[0][nt], 0, 0, 0);
                acc[1][nt] = __builtin_amdgcn_mfma_f32_32x32x16_bf16(a1, bb, acc[1][nt], 0, 0, 0);
            }
        }
        __syncthreads();
    }

    // epilogue: D col = lane&31 (w), row = (reg&3)+8*(reg>>2)+4*kh (cout offset)
    int d = dt * 2 + z, w = wt * 32 + nlo;
    #pragma unroll
    for (int mt = 0; mt < 2; ++mt) {
        #pragma unroll
        for (int nt = 0; nt < 2; ++nt) {
            int h = ht * 4 + ys + nt;
            size_t sp = (((size_t)d) * 64 + h) * 64 + w;
            #pragma unroll
            for (int reg = 0; reg < 16; ++reg) {
                int o = mt * 32 + (reg & 3) + 8 * (reg >> 2) + 4 * kh;
                out[(((size_t)(b * 64 + o)) << 17) + sp] = acc[mt][nt][reg] + bias[o];
            }
        }
    }
}

extern "C" void kernel_launch(void* const* d_in, const int* in_sizes, int n_in,
                              void* d_out, int out_size, void* d_ws, size_t ws_size,
                              hipStream_t stream) {
    const float* x        = (const float*)d_in[0];
    const float* stencils = (const float*)d_in[1];
    const float* weight   = (const float*)d_in[2];
    const float* bias     = (const float*)d_in[3];
    float* out = (float*)d_out;

    uint4* xtbuf = (uint4*)d_ws;
    uint4* keffg = (uint4*)((char*)d_ws + XT_BYTES);

    prep_x<<<dim3(66, 34, 4), 256, 0, stream>>>(x, xtbuf);
    prep_keff<<<108, 256, 0, stream>>>(stencils, weight, keffg);
    conv_mfma<<<2048, 256, 0, stream>>>(xtbuf, keffg, bias, out);
}

// Round 3
// 252.822 us; speedup vs baseline: 4.7341x; 1.0201x over previous
//
#include <hip/hip_runtime.h>

typedef short bf16x8 __attribute__((ext_vector_type(8)));
typedef float f32x16 __attribute__((ext_vector_type(16)));

typedef const __attribute__((address_space(1))) unsigned int GUint;
typedef __attribute__((address_space(3))) unsigned int LUint;

#define XT_BYTES 37914624ull   // 4b * 34zp * 66yp * 66xp * 64B
#define XROW 2176              // 34 xp * 64B per (z,y) LDS row

__device__ __forceinline__ unsigned short f2bf(float f) {
    unsigned u = __float_as_uint(f);
    return (unsigned short)((u + 0x7FFFu + ((u >> 16) & 1u)) >> 16);
}

// ---- pass 1: pad+transpose x (B,Cin,D,H,W) fp32 -> xt[b][zp][yp][xp][c] bf16.
// 16B chunk q of point xp stored at slot q ^ ((xp>>1)&3)  (LDS-bank swizzle).
// Thread map: q fastest -> writes are 16B-consecutive (dense lines); reads are
// 4 dense 64B segments per instruction.
__global__ __launch_bounds__(256) void prep_x(const float* __restrict__ x,
                                              uint4* __restrict__ xt) {
    int yp = blockIdx.x;    // 0..65
    int zp = blockIdx.y;    // 0..33
    int b  = blockIdx.z;    // 0..3
    int t  = threadIdx.x;
    size_t rowbase = ((((size_t)b * 34 + zp) * 66 + yp) * 66) * 4;  // uint4 units
    bool in_zy = (zp >= 1 && zp <= 32 && yp >= 1 && yp <= 64);
    for (int idx = t; idx < 264; idx += 256) {
        int q = idx & 3, xp = idx >> 2;
        uint4 v = make_uint4(0u, 0u, 0u, 0u);
        if (in_zy && xp >= 1 && xp <= 64) {
            int d = zp - 1, h = yp - 1, w = xp - 1;
            const float* xb = x + ((((size_t)b * 32 + q * 8) * 32 + d) * 64 + h) * 64 + w;
            unsigned short us[8];
            #pragma unroll
            for (int j = 0; j < 8; ++j)
                us[j] = f2bf(xb[(size_t)j * 131072]);
            v.x = us[0] | ((unsigned)us[1] << 16);
            v.y = us[2] | ((unsigned)us[3] << 16);
            v.z = us[4] | ((unsigned)us[5] << 16);
            v.w = us[6] | ((unsigned)us[7] << 16);
        }
        int pos = q ^ ((xp >> 1) & 3);
        xt[rowbase + (size_t)xp * 4 + pos] = v;
    }
}

// ---- pass 2: keff in A-fragment order: kf2[b][r][s][mt][lane] (16B chunks).
// lane chunk holds keff[o][c..c+7], o = (lane&31)+32*mt, c = s*16+(lane>>5)*8.
// Unswizzled: conv reads it straight from global (L2-resident, 1KB dense/wave).
__global__ __launch_bounds__(256) void prep_keff(const float* __restrict__ stencils,
                                                 const float* __restrict__ weight,
                                                 uint4* __restrict__ kf2) {
    int i = blockIdx.x * 256 + threadIdx.x;   // 4*27*2*2*64 = 27648 chunks
    if (i >= 27648) return;
    int lane = i & 63;
    int mt = (i >> 6) & 1;
    int s  = (i >> 7) & 1;
    int br = i >> 8;
    int r = br % 27, b = br / 27;
    int o  = (lane & 31) + 32 * mt;
    int cb = s * 16 + (lane >> 5) * 8;
    float st[8];
    #pragma unroll
    for (int t = 0; t < 8; ++t) st[t] = stencils[((size_t)b * 8 + t) * 27 + r];
    unsigned short us[8];
    #pragma unroll
    for (int j = 0; j < 8; ++j) {
        const float* wp = weight + ((size_t)o * 32 + cb + j) * 8;
        float acc = 0.f;
        #pragma unroll
        for (int t = 0; t < 8; ++t) acc += wp[t] * st[t];
        us[j] = f2bf(acc);
    }
    uint4 v;
    v.x = us[0] | ((unsigned)us[1] << 16);
    v.y = us[2] | ((unsigned)us[3] << 16);
    v.z = us[4] | ((unsigned)us[5] << 16);
    v.w = us[6] | ((unsigned)us[7] << 16);
    kf2[i] = v;
}

// ---- pass 3: MFMA conv. Block = 64 couts x (2d x 4h x 32w).
// x tile staged once in LDS (52224B); A (keff) fragments streamed global->reg
// with 1-deep prefetch. NO barriers in the K-loop.
__global__ __launch_bounds__(256, 2) void conv_mfma(
    const uint4* __restrict__ xt, const uint4* __restrict__ kf2,
    const float* __restrict__ bias, float* __restrict__ out) {
    __shared__ __align__(1024) char smem[52224];   // 4z * 6y * 34x * 64B

    int n = blockIdx.x;
    int xcd = n & 7, local = n >> 3;
    int dt = local & 15;
    int cmb = (local >> 4) | (xcd << 4);
    int ht = cmb & 15, wt = (cmb >> 4) & 1, b = cmb >> 5;

    int tid = threadIdx.x;
    int lane = tid & 63, wid = tid >> 6;
    int nlo = lane & 31, kh = lane >> 5;

    const char* xtc = (const char*)xt;

    // prologue: stage x tile via async global->LDS (rows: z 0..3, yy 0..5)
    for (int row = wid; row < 24; row += 4) {
        int z = row / 6, yy = row - z * 6;
        size_t gbase = ((((size_t)b * 34 + dt * 2 + z) * 66 + ht * 4 + yy) * 66 + wt * 32) * 64;
        int ldsbase = row * XROW;
        #pragma unroll
        for (int cb = 0; cb < 136; cb += 64) {
            int rem = 136 - cb;
            if (lane < rem) {
                __builtin_amdgcn_global_load_lds(
                    (GUint*)(xtc + gbase + (size_t)(cb + lane) * 16),
                    (LUint*)(smem + ldsbase + cb * 16), 16, 0, 0);
            }
        }
    }

    // per-wave tile: 2 M-tiles (o 0-31/32-63) x 2 N-tiles (rows ys, ys+1)
    int z = wid >> 1;
    int ys = (wid & 1) << 1;

    int Badr[2][3];
    #pragma unroll
    for (int s = 0; s < 2; ++s)
        #pragma unroll
        for (int k3 = 0; k3 < 3; ++k3) {
            int xl = nlo + k3;
            int pos = (s * 2 + kh) ^ ((xl >> 1) & 3);
            Badr[s][k3] = (z * 6 + ys) * XROW + xl * 64 + (pos << 4);
        }

    // A fragment stream base: kf2 + ((b*27 + r)*4 + fi)*64 + lane  (uint4 units)
    const uint4* kfb = kf2 + (size_t)b * 27 * 256 + lane;

    bf16x8 aCur[4], aNxt[4];
    #pragma unroll
    for (int fi = 0; fi < 4; ++fi)
        aCur[fi] = *(const bf16x8*)(kfb + fi * 64);   // overlaps x staging

    f32x16 acc[2][2];
    #pragma unroll
    for (int mt = 0; mt < 2; ++mt)
        #pragma unroll
        for (int nt = 0; nt < 2; ++nt)
            #pragma unroll
            for (int e = 0; e < 16; ++e) acc[mt][nt][e] = 0.f;

    __syncthreads();   // the ONLY barrier

    #pragma unroll
    for (int r = 0; r < 27; ++r) {
        const int i3 = r / 9, j3 = (r / 3) % 3, k3 = r % 3;
        if (r < 26) {
            #pragma unroll
            for (int fi = 0; fi < 4; ++fi)
                aNxt[fi] = *(const bf16x8*)(kfb + ((r + 1) * 4 + fi) * 64);
        }
        #pragma unroll
        for (int s = 0; s < 2; ++s) {
            #pragma unroll
            for (int nt = 0; nt < 2; ++nt) {
                bf16x8 bb = *(const bf16x8*)(smem + (i3 * 6 + j3 + nt) * XROW + Badr[s][k3]);
                acc[0][nt] = __builtin_amdgcn_mfma_f32_32x32x16_bf16(aCur[s * 2 + 0], bb, acc[0][nt], 0, 0, 0);
                acc[1][nt] = __builtin_amdgcn_mfma_f32_32x32x16_bf16(aCur[s * 2 + 1], bb, acc[1][nt], 0, 0, 0);
            }
        }
        if (r < 26) {
            #pragma unroll
            for (int fi = 0; fi < 4; ++fi) aCur[fi] = aNxt[fi];
        }
    }

    // epilogue: D col = lane&31 (w), row = (reg&3)+8*(reg>>2)+4*kh (cout offset)
    int d = dt * 2 + z, w = wt * 32 + nlo;
    #pragma unroll
    for (int mt = 0; mt < 2; ++mt) {
        #pragma unroll
        for (int nt = 0; nt < 2; ++nt) {
            int h = ht * 4 + ys + nt;
            size_t sp = (((size_t)d) * 64 + h) * 64 + w;
            #pragma unroll
            for (int reg = 0; reg < 16; ++reg) {
                int o = mt * 32 + (reg & 3) + 8 * (reg >> 2) + 4 * kh;
                out[(((size_t)(b * 64 + o)) << 17) + sp] = acc[mt][nt][reg] + bias[o];
            }
        }
    }
}

extern "C" void kernel_launch(void* const* d_in, const int* in_sizes, int n_in,
                              void* d_out, int out_size, void* d_ws, size_t ws_size,
                              hipStream_t stream) {
    const float* x        = (const float*)d_in[0];
    const float* stencils = (const float*)d_in[1];
    const float* weight   = (const float*)d_in[2];
    const float* bias     = (const float*)d_in[3];
    float* out = (float*)d_out;

    uint4* xtbuf = (uint4*)d_ws;
    uint4* kf2   = (uint4*)((char*)d_ws + XT_BYTES);

    prep_x<<<dim3(66, 34, 4), 256, 0, stream>>>(x, xtbuf);
    prep_keff<<<108, 256, 0, stream>>>(stencils, weight, kf2);
    conv_mfma<<<2048, 256, 0, stream>>>(xtbuf, kf2, bias, out);
}

// Round 4
// 250.705 us; speedup vs baseline: 4.7741x; 1.0084x over previous
//
#include <hip/hip_runtime.h>

typedef short bf16x8 __attribute__((ext_vector_type(8)));
typedef float f32x16 __attribute__((ext_vector_type(16)));

#define XROW 2176              // 34 xp * 64B per (z,y) LDS row

__device__ __forceinline__ unsigned short f2bf(float f) {
    unsigned u = __float_as_uint(f);
    return (unsigned short)((u + 0x7FFFu + ((u >> 16) & 1u)) >> 16);
}

// ---- pass 1: keff in A-fragment order: kf2[b][r][s][mt][lane] (16B chunks).
// lane chunk holds keff[o][c..c+7], o = (lane&31)+32*mt, c = s*16+(lane>>5)*8.
// Unswizzled: conv reads it straight from global (L2-resident, 1KB dense/wave).
__global__ __launch_bounds__(256) void prep_keff(const float* __restrict__ stencils,
                                                 const float* __restrict__ weight,
                                                 uint4* __restrict__ kf2) {
    int i = blockIdx.x * 256 + threadIdx.x;   // 4*27*2*2*64 = 27648 chunks
    if (i >= 27648) return;
    int lane = i & 63;
    int mt = (i >> 6) & 1;
    int s  = (i >> 7) & 1;
    int br = i >> 8;
    int r = br % 27, b = br / 27;
    int o  = (lane & 31) + 32 * mt;
    int cb = s * 16 + (lane >> 5) * 8;
    float st[8];
    #pragma unroll
    for (int t = 0; t < 8; ++t) st[t] = stencils[((size_t)b * 8 + t) * 27 + r];
    unsigned short us[8];
    #pragma unroll
    for (int j = 0; j < 8; ++j) {
        const float* wp = weight + ((size_t)o * 32 + cb + j) * 8;
        float acc = 0.f;
        #pragma unroll
        for (int t = 0; t < 8; ++t) acc += wp[t] * st[t];
        us[j] = f2bf(acc);
    }
    uint4 v;
    v.x = us[0] | ((unsigned)us[1] << 16);
    v.y = us[2] | ((unsigned)us[3] << 16);
    v.z = us[4] | ((unsigned)us[5] << 16);
    v.w = us[6] | ((unsigned)us[7] << 16);
    kf2[i] = v;
}

// ---- pass 2: fused transpose + MFMA conv. Block = 64 couts x (2d x 4h x 32w).
// Prologue gathers the fp32 halo tile (channel-strided), converts to bf16,
// writes the swizzled LDS tile directly (no xt intermediate in HBM).
// K-loop: A (keff) streamed global->reg 1-deep prefetch; NO barriers.
__global__ __launch_bounds__(256, 2) void conv_fused(
    const float* __restrict__ x, const uint4* __restrict__ kf2,
    const float* __restrict__ bias, float* __restrict__ out) {
    __shared__ __align__(1024) char smem[52224];   // 4z * 6y * 34xp * 64B

    int n = blockIdx.x;
    int xcd = n & 7, local = n >> 3;
    int dt = local & 15;
    int cmb = (local >> 4) | (xcd << 4);
    int ht = cmb & 15, wt = (cmb >> 4) & 1, b = cmb >> 5;

    int tid = threadIdx.x;
    int lane = tid & 63, wid = tid >> 6;
    int nlo = lane & 31, kh = lane >> 5;

    // ---- prologue: gather + transpose + convert x tile into LDS.
    // 24 rows (z 0..3, yy 0..5) x 34 xp x 4 chunks = 3264 chunk-tasks.
    for (int task = tid; task < 3264; task += 256) {
        int row = task / 136;               // 0..23
        int chunk = task - row * 136;       // 0..135
        int q = chunk & 3, xp = chunk >> 2; // chunk q of point xp
        int z = row / 6, yy = row - z * 6;
        int gd = dt * 2 + z - 1, gh = ht * 4 + yy - 1, gw = wt * 32 + xp - 1;
        uint4 v = make_uint4(0u, 0u, 0u, 0u);
        if ((unsigned)gd < 32u && (unsigned)gh < 64u && (unsigned)gw < 64u) {
            const float* xb = x + (((size_t)(b * 32 + q * 8) * 32 + gd) * 64 + gh) * 64 + gw;
            unsigned short us[8];
            #pragma unroll
            for (int j = 0; j < 8; ++j)
                us[j] = f2bf(xb[(size_t)j * 131072]);
            v.x = us[0] | ((unsigned)us[1] << 16);
            v.y = us[2] | ((unsigned)us[3] << 16);
            v.z = us[4] | ((unsigned)us[5] << 16);
            v.w = us[6] | ((unsigned)us[7] << 16);
        }
        int pos = q ^ ((xp >> 1) & 3);
        *(uint4*)(smem + row * XROW + xp * 64 + (pos << 4)) = v;
    }

    // per-wave tile: 2 M-tiles (o 0-31/32-63) x 2 N-tiles (rows ys, ys+1)
    int z = wid >> 1;
    int ys = (wid & 1) << 1;

    int Badr[2][3];
    #pragma unroll
    for (int s = 0; s < 2; ++s)
        #pragma unroll
        for (int k3 = 0; k3 < 3; ++k3) {
            int xl = nlo + k3;
            int pos = (s * 2 + kh) ^ ((xl >> 1) & 3);
            Badr[s][k3] = (z * 6 + ys) * XROW + xl * 64 + (pos << 4);
        }

    // A fragment stream base: kf2 + ((b*27 + r)*4 + fi)*64 + lane  (uint4 units)
    const uint4* kfb = kf2 + (size_t)b * 27 * 256 + lane;

    bf16x8 aCur[4], aNxt[4];
    #pragma unroll
    for (int fi = 0; fi < 4; ++fi)
        aCur[fi] = *(const bf16x8*)(kfb + fi * 64);   // overlaps staging

    f32x16 acc[2][2];
    #pragma unroll
    for (int mt = 0; mt < 2; ++mt)
        #pragma unroll
        for (int nt = 0; nt < 2; ++nt)
            #pragma unroll
            for (int e = 0; e < 16; ++e) acc[mt][nt][e] = 0.f;

    __syncthreads();   // the ONLY barrier

    #pragma unroll
    for (int r = 0; r < 27; ++r) {
        const int i3 = r / 9, j3 = (r / 3) % 3, k3 = r % 3;
        if (r < 26) {
            #pragma unroll
            for (int fi = 0; fi < 4; ++fi)
                aNxt[fi] = *(const bf16x8*)(kfb + ((r + 1) * 4 + fi) * 64);
        }
        #pragma unroll
        for (int s = 0; s < 2; ++s) {
            #pragma unroll
            for (int nt = 0; nt < 2; ++nt) {
                bf16x8 bb = *(const bf16x8*)(smem + (i3 * 6 + j3 + nt) * XROW + Badr[s][k3]);
                acc[0][nt] = __builtin_amdgcn_mfma_f32_32x32x16_bf16(aCur[s * 2 + 0], bb, acc[0][nt], 0, 0, 0);
                acc[1][nt] = __builtin_amdgcn_mfma_f32_32x32x16_bf16(aCur[s * 2 + 1], bb, acc[1][nt], 0, 0, 0);
            }
        }
        if (r < 26) {
            #pragma unroll
            for (int fi = 0; fi < 4; ++fi) aCur[fi] = aNxt[fi];
        }
    }

    // epilogue: D col = lane&31 (w), row = (reg&3)+8*(reg>>2)+4*kh (cout offset)
    int d = dt * 2 + z, w = wt * 32 + nlo;
    #pragma unroll
    for (int mt = 0; mt < 2; ++mt) {
        #pragma unroll
        for (int nt = 0; nt < 2; ++nt) {
            int h = ht * 4 + ys + nt;
            size_t sp = (((size_t)d) * 64 + h) * 64 + w;
            #pragma unroll
            for (int reg = 0; reg < 16; ++reg) {
                int o = mt * 32 + (reg & 3) + 8 * (reg >> 2) + 4 * kh;
                out[(((size_t)(b * 64 + o)) << 17) + sp] = acc[mt][nt][reg] + bias[o];
            }
        }
    }
}

extern "C" void kernel_launch(void* const* d_in, const int* in_sizes, int n_in,
                              void* d_out, int out_size, void* d_ws, size_t ws_size,
                              hipStream_t stream) {
    const float* x        = (const float*)d_in[0];
    const float* stencils = (const float*)d_in[1];
    const float* weight   = (const float*)d_in[2];
    const float* bias     = (const float*)d_in[3];
    float* out = (float*)d_out;

    uint4* kf2 = (uint4*)d_ws;   // 432 KB

    prep_keff<<<108, 256, 0, stream>>>(stencils, weight, kf2);
    conv_fused<<<2048, 256, 0, stream>>>(x, kf2, bias, out);
}